// Round 7
// baseline (1044.581 us; speedup 1.0000x reference)
//
#include <hip/hip_runtime.h>
#include <hip/hip_bf16.h>
#include <cstdint>
#include <cstddef>

#define T_DIM 2048
#define B_DIM 32
#define D_DIM 512
#define H_DIM 768
#define C_DIM 10
#define K_DIM D_DIM             /* 512  */
#define N_DIM (4 * H_DIM)       /* 3072 */

#define TC 1024                 /* timesteps per chunk */
#define NCHUNK (T_DIM / TC)     /* 2 */
#define MC (TC * B_DIM)         /* 32768 rows per chunk GEMM */

#define L_SEG 64                /* scan segment length */
#define S_SEG (TC / L_SEG)      /* 16 segments per chunk */
#define BH (B_DIM * H_DIM)      /* 24576 chains */

typedef __attribute__((ext_vector_type(8))) short short8;
typedef __attribute__((ext_vector_type(4))) float float4v;

__device__ inline unsigned short f2bf(float f) {
  unsigned int u = __builtin_bit_cast(unsigned int, f);
  unsigned int r = (u + 0x7FFFu + ((u >> 16) & 1u)) >> 16;
  return (unsigned short)r;
}
__device__ inline float bf2f(unsigned short s) {
  unsigned int u = ((unsigned int)s) << 16;
  return __builtin_bit_cast(float, u);
}
__device__ inline float fast_rcp(float x) { return __builtin_amdgcn_rcpf(x); }
__device__ inline float fast_exp2(float x) { return __builtin_amdgcn_exp2f(x); }
__device__ inline float sigmoid_f(float x) {
  float e = fast_exp2(-1.4426950408889634f * x);
  return fast_rcp(1.0f + e);
}
__device__ inline float tanh_f(float x) {
  float e = fast_exp2(2.885390081777927f * x);
  return 1.0f - 2.0f * fast_rcp(e + 1.0f);
}
__device__ inline unsigned int pack_bf16x2(float lo, float hi) {
  return ((unsigned int)f2bf(hi) << 16) | (unsigned int)f2bf(lo);
}

// ---------------------------------------------------------------------------
// Kernel 1: chunked embedding gather + fp32->bf16
// ---------------------------------------------------------------------------
__global__ __launch_bounds__(256) void gather_embed_kernel(
    const int* __restrict__ x_c, const float* __restrict__ table,
    unsigned short* __restrict__ ebfc) {
  int idx = blockIdx.x * 256 + threadIdx.x;
  int m = idx >> 7;
  int k4 = (idx & 127) << 2;
  int row = x_c[m];
  float4 v = *(const float4*)(table + (size_t)row * D_DIM + k4);
  ushort4 o;
  o.x = f2bf(v.x); o.y = f2bf(v.y); o.z = f2bf(v.z); o.w = f2bf(v.w);
  *(ushort4*)(ebfc + (size_t)m * D_DIM + k4) = o;
}

// ---------------------------------------------------------------------------
// Kernel 2: concat 4 weight matrices -> bf16  wcat[n][k], n: [Wx;Wf;Wr;Wcx]
// ---------------------------------------------------------------------------
__global__ __launch_bounds__(256) void convert_w_kernel(
    const float* __restrict__ Wx, const float* __restrict__ Wf,
    const float* __restrict__ Wr, const float* __restrict__ Wcx,
    unsigned short* __restrict__ wcat) {
  int idx = blockIdx.x * 256 + threadIdx.x;
  int n = idx >> 7;
  int k4 = (idx & 127) << 2;
  int mat = n / H_DIM;
  int h = n - mat * H_DIM;
  const float* src = (mat == 0) ? Wx : (mat == 1) ? Wf : (mat == 2) ? Wr : Wcx;
  float4 v = *(const float4*)(src + (size_t)h * D_DIM + k4);
  ushort4 o;
  o.x = f2bf(v.x); o.y = f2bf(v.y); o.z = f2bf(v.z); o.w = f2bf(v.w);
  *(ushort4*)(wcat + (size_t)n * D_DIM + k4) = o;
}

// ---------------------------------------------------------------------------
// Kernel 3: bf16 MFMA GEMM — LDS-free, barrier-free.
// Both operands loaded as MFMA fragments directly from global:
//   fragment row = l16, k-chunk = quad  ->  each wave load instr covers
//   16 rows x 64 B = 16 full cache lines (dense coalescing).
// Weights (3 MB) are L2-resident; activations L2/LLC-warm; wave-pair
// duplicate fragment loads hit L1. Ping-pong registers prefetch iter ki+1
// during iter ki's MFMAs — no __syncthreads, no vmcnt(0) drain anywhere.
// A-operand = weights, B-operand = activations => C/D: col=lane&15=m,
// row=quad*4+reg = 4 consecutive h at fixed m -> packed 8B direct stores.
// ---------------------------------------------------------------------------
#define BM 128
#define BN 128
#define BK 32

__global__ __launch_bounds__(256, 3) void gemm_kernel(
    const unsigned short* __restrict__ ebfc,
    const unsigned short* __restrict__ wcat,
    const float* __restrict__ b_f, const float* __restrict__ b_r,
    const float* __restrict__ b_cx,
    unsigned short* __restrict__ projc) {
  int tid  = threadIdx.x;
  int wave = tid >> 6;
  int lane = tid & 63;
  int quad = lane >> 4;
  int l16  = lane & 15;
  int m0 = blockIdx.y * BM;
  int n0 = blockIdx.x * BN;
  int wn = (wave & 1) * 64;        // h-subtile of wave
  int wm = (wave >> 1) * 64;       // m-subtile of wave

  const unsigned short* aw[4];     // weight-fragment base ptrs
  const unsigned short* ae[4];     // activation-fragment base ptrs
#pragma unroll
  for (int i = 0; i < 4; i++)
    aw[i] = wcat + (size_t)(n0 + wn + i * 16 + l16) * K_DIM + quad * 8;
#pragma unroll
  for (int j = 0; j < 4; j++)
    ae[j] = ebfc + (size_t)(m0 + wm + j * 16 + l16) * K_DIM + quad * 8;

  float4v acc[4][4] = {};
  short8 wf[2][4], ef[2][4];
#pragma unroll
  for (int i = 0; i < 4; i++) {
    wf[0][i] = *(const short8*)(aw[i]);
    ef[0][i] = *(const short8*)(ae[i]);
  }

#pragma unroll
  for (int ki = 0; ki < K_DIM / BK; ki++) {
    const int cur = ki & 1, nxt = cur ^ 1;
    if (ki + 1 < K_DIM / BK) {
      const int ko = (ki + 1) * BK;
#pragma unroll
      for (int i = 0; i < 4; i++) {
        wf[nxt][i] = *(const short8*)(aw[i] + ko);
        ef[nxt][i] = *(const short8*)(ae[i] + ko);
      }
    }
#pragma unroll
    for (int i = 0; i < 4; i++)
#pragma unroll
      for (int j = 0; j < 4; j++)
        acc[i][j] = __builtin_amdgcn_mfma_f32_16x16x32_bf16(wf[cur][i], ef[cur][j], acc[i][j], 0, 0, 0);
  }

  // ---- epilogue: bias/sigmoid + packed bf16 + direct 8B stores ----
  int mat = n0 / H_DIM;                    // uniform per block
  int hb = n0 - mat * H_DIM;
  size_t matBase = (size_t)mat * MC * H_DIM;
  const float* bias = (mat == 1) ? b_f : (mat == 2) ? b_r : b_cx;
#pragma unroll
  for (int i = 0; i < 4; i++) {
    int h0 = hb + wn + i * 16 + quad * 4;  // 4 consecutive h per lane
    float4 bv;
    if (mat == 0) { bv.x = bv.y = bv.z = bv.w = 0.0f; }
    else          { bv = *(const float4*)(bias + h0); }
#pragma unroll
    for (int j = 0; j < 4; j++) {
      int m = m0 + wm + j * 16 + l16;
      float v0 = acc[i][j][0] + bv.x;
      float v1 = acc[i][j][1] + bv.y;
      float v2 = acc[i][j][2] + bv.z;
      float v3 = acc[i][j][3] + bv.w;
      if (mat == 1 || mat == 2) {
        v0 = sigmoid_f(v0); v1 = sigmoid_f(v1);
        v2 = sigmoid_f(v2); v3 = sigmoid_f(v3);
      }
      uint2 pk;
      pk.x = pack_bf16x2(v0, v1);
      pk.y = pack_bf16x2(v2, v3);
      *(uint2*)(projc + matBase + (size_t)m * H_DIM + h0) = pk;
    }
  }
}

// ---------------------------------------------------------------------------
// Kernel 4a (scan1): per-segment summaries P = prod f, Q = c_out given c_in=0.
// thread <-> (seg, 4 consecutive (b,h) flat). 768 blocks x 128 threads.
// ---------------------------------------------------------------------------
__global__ __launch_bounds__(128) void scan1_kernel(
    const unsigned short* __restrict__ projc,
    float* __restrict__ Pw, float* __restrict__ Qw) {
  int blk = blockIdx.x;
  int seg = blk / (BH / 512);             // BH/4/128 = 48 blocks per seg
  int q   = blk % (BH / 512);
  int e4  = (q * 128 + threadIdx.x) * 4;  // flat (b*H + h) base, 4 wide
  const size_t mstr = (size_t)MC * H_DIM;
  size_t idx0 = (size_t)(seg * L_SEG) * BH + e4;
  float p0 = 1.f, p1 = 1.f, p2 = 1.f, p3 = 1.f;
  float c0 = 0.f, c1 = 0.f, c2 = 0.f, c3 = 0.f;
#pragma unroll 4
  for (int t = 0; t < L_SEG; t++) {
    size_t id = idx0 + (size_t)t * BH;
    ushort4 xp = *(const ushort4*)(projc + id);
    ushort4 ff = *(const ushort4*)(projc + mstr + id);
    float f0 = bf2f(ff.x), f1 = bf2f(ff.y), f2 = bf2f(ff.z), f3 = bf2f(ff.w);
    c0 = fmaf(f0, c0 - bf2f(xp.x), bf2f(xp.x));
    c1 = fmaf(f1, c1 - bf2f(xp.y), bf2f(xp.y));
    c2 = fmaf(f2, c2 - bf2f(xp.z), bf2f(xp.z));
    c3 = fmaf(f3, c3 - bf2f(xp.w), bf2f(xp.w));
    p0 *= f0; p1 *= f1; p2 *= f2; p3 *= f3;
  }
  int o = seg * BH + e4;
  *(float4*)(Pw + o) = make_float4(p0, p1, p2, p3);
  *(float4*)(Qw + o) = make_float4(c0, c1, c2, c3);
}

// ---------------------------------------------------------------------------
// Kernel 4b (prefix): chain segments exactly: c_out = P*c_in + Q.
// Also folds previous chunk's segmax into hm_state. 96 blocks x 256.
// ---------------------------------------------------------------------------
__global__ __launch_bounds__(256) void prefix_kernel(
    const float* __restrict__ Pw, const float* __restrict__ Qw,
    float* __restrict__ cin, float* __restrict__ c_state,
    const float* __restrict__ segmax, float* __restrict__ hm_state,
    int first, int hm_init) {
  int gid = blockIdx.x * 256 + threadIdx.x;
  float c = first ? 0.f : c_state[gid];
#pragma unroll
  for (int s = 0; s < S_SEG; s++) {
    cin[s * BH + gid] = c;
    c = fmaf(Pw[s * BH + gid], c, Qw[s * BH + gid]);
  }
  c_state[gid] = c;
  if (!first) {
    float m = segmax[gid];
#pragma unroll
    for (int s = 1; s < S_SEG; s++) m = fmaxf(m, segmax[s * BH + gid]);
    hm_state[gid] = hm_init ? m : fmaxf(hm_state[gid], m);
  }
}

// ---------------------------------------------------------------------------
// Kernel 4c (scan2): replay each segment from true c_in; h + segment max.
// ---------------------------------------------------------------------------
__global__ __launch_bounds__(128) void scan2_kernel(
    const unsigned short* __restrict__ projc,
    const float* __restrict__ cin, float* __restrict__ segmax) {
  int blk = blockIdx.x;
  int seg = blk / (BH / 512);
  int q   = blk % (BH / 512);
  int e4  = (q * 128 + threadIdx.x) * 4;
  const size_t mstr = (size_t)MC * H_DIM;
  size_t idx0 = (size_t)(seg * L_SEG) * BH + e4;
  int o = seg * BH + e4;
  float4 cv = *(const float4*)(cin + o);
  float c0 = cv.x, c1 = cv.y, c2 = cv.z, c3 = cv.w;
  float m0 = -1e30f, m1 = -1e30f, m2 = -1e30f, m3 = -1e30f;
#pragma unroll 2
  for (int t = 0; t < L_SEG; t++) {
    size_t id = idx0 + (size_t)t * BH;
    ushort4 xp = *(const ushort4*)(projc + id);
    ushort4 ff = *(const ushort4*)(projc + mstr + id);
    ushort4 rr = *(const ushort4*)(projc + 2 * mstr + id);
    ushort4 cx = *(const ushort4*)(projc + 3 * mstr + id);
    c0 = fmaf(bf2f(ff.x), c0 - bf2f(xp.x), bf2f(xp.x));
    c1 = fmaf(bf2f(ff.y), c1 - bf2f(xp.y), bf2f(xp.y));
    c2 = fmaf(bf2f(ff.z), c2 - bf2f(xp.z), bf2f(xp.z));
    c3 = fmaf(bf2f(ff.w), c3 - bf2f(xp.w), bf2f(xp.w));
    float h0 = fmaf(bf2f(rr.x), tanh_f(c0) - bf2f(cx.x), bf2f(cx.x));
    float h1 = fmaf(bf2f(rr.y), tanh_f(c1) - bf2f(cx.y), bf2f(cx.y));
    float h2 = fmaf(bf2f(rr.z), tanh_f(c2) - bf2f(cx.z), bf2f(cx.z));
    float h3 = fmaf(bf2f(rr.w), tanh_f(c3) - bf2f(cx.w), bf2f(cx.w));
    m0 = fmaxf(m0, h0); m1 = fmaxf(m1, h1);
    m2 = fmaxf(m2, h2); m3 = fmaxf(m3, h3);
  }
  *(float4*)(segmax + o) = make_float4(m0, m1, m2, m3);
}

// ---------------------------------------------------------------------------
// Kernel 4d: final pool = tanh(tanh(max(hm_state, last chunk's segmax)))
// ---------------------------------------------------------------------------
__global__ __launch_bounds__(256) void pool_final_kernel(
    const float* __restrict__ segmax, const float* __restrict__ hm_state,
    float* __restrict__ pooled) {
  int gid = blockIdx.x * 256 + threadIdx.x;
  float m = hm_state[gid];
#pragma unroll
  for (int s = 0; s < S_SEG; s++) m = fmaxf(m, segmax[s * BH + gid]);
  pooled[gid] = tanh_f(tanh_f(m));
}

// ---------------------------------------------------------------------------
// Kernel 5: classifier  logit[b][c] = pooled[b]·W_out[c] + b_out[c]
// ---------------------------------------------------------------------------
__global__ __launch_bounds__(64) void classifier_kernel(
    const float* __restrict__ pooled, const float* __restrict__ W_out,
    const float* __restrict__ b_out, float* __restrict__ out) {
  int b = blockIdx.x / C_DIM;
  int c = blockIdx.x % C_DIM;
  int lane = threadIdx.x;
  float s = 0.0f;
#pragma unroll
  for (int i = 0; i < H_DIM / 64; i++) {
    int h = i * 64 + lane;
    s += pooled[(size_t)b * H_DIM + h] * W_out[(size_t)c * H_DIM + h];
  }
#pragma unroll
  for (int off = 32; off; off >>= 1) s += __shfl_down(s, off, 64);
  if (lane == 0) out[b * C_DIM + c] = s + b_out[c];
}

// ---------------------------------------------------------------------------
extern "C" void kernel_launch(void* const* d_in, const int* in_sizes, int n_in,
                              void* d_out, int out_size, void* d_ws, size_t ws_size,
                              hipStream_t stream) {
  const int*   x     = (const int*)d_in[0];
  const float* table = (const float*)d_in[1];
  const float* W_x   = (const float*)d_in[2];
  const float* W_f   = (const float*)d_in[3];
  const float* b_f   = (const float*)d_in[4];
  const float* W_r   = (const float*)d_in[5];
  const float* b_r   = (const float*)d_in[6];
  const float* W_cx  = (const float*)d_in[7];
  const float* b_cx  = (const float*)d_in[8];
  const float* W_out = (const float*)d_in[9];
  const float* b_out = (const float*)d_in[10];

  // workspace layout (~245 MB; ws_size ~411 MB per harness fill size)
  char* ws = (char*)d_ws;
  size_t off = 0;
  unsigned short* wcat  = (unsigned short*)(ws + off); off += (size_t)N_DIM * K_DIM * 2;
  unsigned short* ebfc  = (unsigned short*)(ws + off); off += (size_t)MC * K_DIM * 2;
  unsigned short* projc = (unsigned short*)(ws + off); off += (size_t)4 * MC * H_DIM * 2;
  float* Pw     = (float*)(ws + off); off += (size_t)S_SEG * BH * 4;
  float* Qw     = (float*)(ws + off); off += (size_t)S_SEG * BH * 4;
  float* cin    = (float*)(ws + off); off += (size_t)S_SEG * BH * 4;
  float* segmax = (float*)(ws + off); off += (size_t)S_SEG * BH * 4;
  float* c_st   = (float*)(ws + off); off += (size_t)BH * 4;
  float* hm_st  = (float*)(ws + off); off += (size_t)BH * 4;
  float* pooled = (float*)(ws + off); off += (size_t)BH * 4;

  convert_w_kernel<<<(N_DIM * K_DIM / 4) / 256, 256, 0, stream>>>(W_x, W_f, W_r, W_cx, wcat);

  dim3 g(N_DIM / BN, MC / BM);   // (24, 256)
  for (int ch = 0; ch < NCHUNK; ch++) {
    gather_embed_kernel<<<(MC * K_DIM / 4) / 256, 256, 0, stream>>>(x + (size_t)ch * MC, table, ebfc);
    gemm_kernel<<<g, 256, 0, stream>>>(ebfc, wcat, b_f, b_r, b_cx, projc);
    scan1_kernel<<<S_SEG * (BH / 512), 128, 0, stream>>>(projc, Pw, Qw);
    prefix_kernel<<<BH / 256, 256, 0, stream>>>(Pw, Qw, cin, c_st, segmax, hm_st,
                                                ch == 0, ch == 1);
    scan2_kernel<<<S_SEG * (BH / 512), 128, 0, stream>>>(projc, cin, segmax);
  }
  pool_final_kernel<<<BH / 256, 256, 0, stream>>>(segmax, hm_st, pooled);
  classifier_kernel<<<B_DIM * C_DIM, 64, 0, stream>>>(pooled, W_out, b_out, (float*)d_out);
}

// Round 8
// 546.752 us; speedup vs baseline: 1.9105x; 1.9105x over previous
//
#include <hip/hip_runtime.h>
#include <hip/hip_bf16.h>
#include <cstdint>
#include <cstddef>

#define T_DIM 2048
#define B_DIM 32
#define D_DIM 512
#define H_DIM 768
#define C_DIM 10
#define K_DIM D_DIM             /* 512  */
#define N_DIM (4 * H_DIM)       /* 3072 */

#define TC 1024                 /* timesteps per chunk */
#define NCHUNK (T_DIM / TC)     /* 2 */
#define MC (TC * B_DIM)         /* 32768 rows per chunk GEMM */

#define L_SEG 64                /* scan segment length */
#define S_SEG (TC / L_SEG)      /* 16 segments per chunk */
#define BH (B_DIM * H_DIM)      /* 24576 chains */

typedef __attribute__((ext_vector_type(8))) short short8;
typedef __attribute__((ext_vector_type(4))) float float4v;

__device__ inline unsigned short f2bf(float f) {
  unsigned int u = __builtin_bit_cast(unsigned int, f);
  unsigned int r = (u + 0x7FFFu + ((u >> 16) & 1u)) >> 16;
  return (unsigned short)r;
}
__device__ inline float bf2f(unsigned short s) {
  unsigned int u = ((unsigned int)s) << 16;
  return __builtin_bit_cast(float, u);
}
__device__ inline float fast_rcp(float x) { return __builtin_amdgcn_rcpf(x); }
__device__ inline float fast_exp2(float x) { return __builtin_amdgcn_exp2f(x); }
__device__ inline float sigmoid_f(float x) {
  float e = fast_exp2(-1.4426950408889634f * x);
  return fast_rcp(1.0f + e);
}
__device__ inline float tanh_f(float x) {
  float e = fast_exp2(2.885390081777927f * x);
  return 1.0f - 2.0f * fast_rcp(e + 1.0f);
}
__device__ inline void gld16(const unsigned short* g, unsigned short* l) {
  __builtin_amdgcn_global_load_lds(
      (const __attribute__((address_space(1))) void*)g,
      (__attribute__((address_space(3))) void*)l, 16, 0, 0);
}
__device__ inline unsigned int pack_bf16x2(float lo, float hi) {
  return ((unsigned int)f2bf(hi) << 16) | (unsigned int)f2bf(lo);
}

// ---------------------------------------------------------------------------
// Kernel 1: chunked embedding gather + fp32->bf16
// ---------------------------------------------------------------------------
__global__ __launch_bounds__(256) void gather_embed_kernel(
    const int* __restrict__ x_c, const float* __restrict__ table,
    unsigned short* __restrict__ ebfc) {
  int idx = blockIdx.x * 256 + threadIdx.x;
  int m = idx >> 7;
  int k4 = (idx & 127) << 2;
  int row = x_c[m];
  float4 v = *(const float4*)(table + (size_t)row * D_DIM + k4);
  ushort4 o;
  o.x = f2bf(v.x); o.y = f2bf(v.y); o.z = f2bf(v.z); o.w = f2bf(v.w);
  *(ushort4*)(ebfc + (size_t)m * D_DIM + k4) = o;
}

// ---------------------------------------------------------------------------
// Kernel 2: concat 4 weight matrices -> bf16  wcat[n][k], n: [Wx;Wf;Wr;Wcx]
// ---------------------------------------------------------------------------
__global__ __launch_bounds__(256) void convert_w_kernel(
    const float* __restrict__ Wx, const float* __restrict__ Wf,
    const float* __restrict__ Wr, const float* __restrict__ Wcx,
    unsigned short* __restrict__ wcat) {
  int idx = blockIdx.x * 256 + threadIdx.x;
  int n = idx >> 7;
  int k4 = (idx & 127) << 2;
  int mat = n / H_DIM;
  int h = n - mat * H_DIM;
  const float* src = (mat == 0) ? Wx : (mat == 1) ? Wf : (mat == 2) ? Wr : Wcx;
  float4 v = *(const float4*)(src + (size_t)h * D_DIM + k4);
  ushort4 o;
  o.x = f2bf(v.x); o.y = f2bf(v.y); o.z = f2bf(v.z); o.w = f2bf(v.w);
  *(ushort4*)(wcat + (size_t)n * D_DIM + k4) = o;
}

// ---------------------------------------------------------------------------
// Kernel 3: bf16 MFMA GEMM (round-6 LDS-dbuf structure + occupancy push).
// A-operand = weights, B-operand = activations => C/D: col=lane&15=m,
// row=quad*4+reg = 4 consecutive h at fixed m.
// __launch_bounds__(256,4): cap regs to <=128/wave (64 AGPR acc + ~60 V) so
// 4 blocks/CU co-reside (vs 2.56 measured in round 6) to hide the
// barrier-drain load latency.
// Epilogue: bias/sigmoid -> swizzled LDS transpose (stride 128 shorts,
// chunk ^ (row&7): 2-way banks = free) -> perfectly coalesced 16B stores.
// Reuses the 32KB staging LDS after the last barrier.
// ---------------------------------------------------------------------------
#define BM 128
#define BN 128
#define BK 32

__global__ __launch_bounds__(256, 4) void gemm_kernel(
    const unsigned short* __restrict__ ebfc,
    const unsigned short* __restrict__ wcat,
    const float* __restrict__ b_f, const float* __restrict__ b_r,
    const float* __restrict__ b_cx,
    unsigned short* __restrict__ projc) {
  __shared__ __align__(16) unsigned short smem[16384];  // 32 KB
  unsigned short* As0 = smem;
  unsigned short* As1 = smem + 4096;
  unsigned short* Bs0 = smem + 8192;
  unsigned short* Bs1 = smem + 12288;

  int tid  = threadIdx.x;
  int wave = tid >> 6;
  int lane = tid & 63;
  int quad = lane >> 4;
  int l16  = lane & 15;
  int m0 = blockIdx.y * BM;
  int n0 = blockIdx.x * BN;
  int wn = (wave & 1) * 64;        // h-subtile of wave
  int wm = (wave >> 1) * 64;       // m-subtile of wave

  int row0 = tid >> 2;
  int cl0  = (tid & 3) ^ ((row0 >> 1) & 3);
  // note: ((64+row0)>>1)&3 == ((row0>>1)&3), so row1 uses the same cl0

  const unsigned short* gA0 = ebfc + (size_t)(m0 + row0) * K_DIM + cl0 * 8;
  const unsigned short* gB0 = wcat + (size_t)(n0 + row0) * K_DIM + cl0 * 8;
  const unsigned short* gA1 = gA0 + (size_t)64 * K_DIM;
  const unsigned short* gB1 = gB0 + (size_t)64 * K_DIM;

  float4v acc[4][4] = {};

#define STAGE(Adst, Bdst, kt) do { \
    gld16(gA0 + (kt), (Adst) + tid * 8); \
    gld16(gB0 + (kt), (Bdst) + tid * 8); \
    gld16(gA1 + (kt), (Adst) + 2048 + tid * 8); \
    gld16(gB1 + (kt), (Bdst) + 2048 + tid * 8); } while (0)

  STAGE(As0, Bs0, 0);
  __syncthreads();

#pragma unroll
  for (int ki = 0; ki < K_DIM / BK; ki++) {
    unsigned short* Ac = (ki & 1) ? As1 : As0;
    unsigned short* Bc = (ki & 1) ? Bs1 : Bs0;
    if (ki + 1 < K_DIM / BK) {
      unsigned short* An = (ki & 1) ? As0 : As1;
      unsigned short* Bn = (ki & 1) ? Bs0 : Bs1;
      STAGE(An, Bn, (ki + 1) * BK);
    }
    short8 wf[4], ef[4];
#pragma unroll
    for (int i = 0; i < 4; i++) {
      int r = wn + i * 16 + l16;
      int p = quad ^ ((r >> 1) & 3);
      wf[i] = *(const short8*)(Bc + r * BK + p * 8);
    }
#pragma unroll
    for (int j = 0; j < 4; j++) {
      int r = wm + j * 16 + l16;
      int p = quad ^ ((r >> 1) & 3);
      ef[j] = *(const short8*)(Ac + r * BK + p * 8);
    }
#pragma unroll
    for (int i = 0; i < 4; i++)
#pragma unroll
      for (int j = 0; j < 4; j++)
        acc[i][j] = __builtin_amdgcn_mfma_f32_16x16x32_bf16(wf[i], ef[j], acc[i][j], 0, 0, 0);
    __syncthreads();
  }

  // ---- epilogue: bias/sigmoid -> swizzled LDS transpose -> 16B stores ----
  int mat = n0 / H_DIM;                    // uniform per block
  int hb = n0 - mat * H_DIM;
  size_t matBase = (size_t)mat * MC * H_DIM;
  const float* bias = (mat == 1) ? b_f : (mat == 2) ? b_r : b_cx;
#pragma unroll
  for (int i = 0; i < 4; i++) {
    int hl = wn + i * 16 + quad * 4;       // local h (0..127), 4 consecutive
    float4 bv;
    if (mat == 0) { bv.x = bv.y = bv.z = bv.w = 0.0f; }
    else          { bv = *(const float4*)(bias + hb + hl); }
#pragma unroll
    for (int j = 0; j < 4; j++) {
      int row = wm + j * 16 + l16;         // local m (0..127)
      float v0 = acc[i][j][0] + bv.x;
      float v1 = acc[i][j][1] + bv.y;
      float v2 = acc[i][j][2] + bv.z;
      float v3 = acc[i][j][3] + bv.w;
      if (mat == 1 || mat == 2) {
        v0 = sigmoid_f(v0); v1 = sigmoid_f(v1);
        v2 = sigmoid_f(v2); v3 = sigmoid_f(v3);
      }
      uint2 pk;
      pk.x = pack_bf16x2(v0, v1);
      pk.y = pack_bf16x2(v2, v3);
      int chunk = (hl >> 3) ^ (row & 7);   // swizzled 8-short chunk
      *(uint2*)(smem + row * 128 + chunk * 8 + (hl & 7)) = pk;
    }
  }
  __syncthreads();
#pragma unroll
  for (int s = 0; s < 8; s++) {
    int idx = s * 256 + tid;
    int row = idx >> 4;                    // local m
    int ck  = idx & 15;                    // logical 8-short chunk of h
    int phys = ck ^ (row & 7);
    short8 v = *(const short8*)(smem + row * 128 + phys * 8);
    *(short8*)(projc + matBase + (size_t)(m0 + row) * H_DIM + hb + ck * 8) = v;
  }
}

// ---------------------------------------------------------------------------
// Kernel 4a (scan1): per-segment summaries P = prod f, Q = c_out given c_in=0.
// thread <-> (seg, 4 consecutive (b,h) flat). 768 blocks x 128 threads.
// ---------------------------------------------------------------------------
__global__ __launch_bounds__(128) void scan1_kernel(
    const unsigned short* __restrict__ projc,
    float* __restrict__ Pw, float* __restrict__ Qw) {
  int blk = blockIdx.x;
  int seg = blk / (BH / 512);             // 48 blocks per seg
  int q   = blk % (BH / 512);
  int e4  = (q * 128 + threadIdx.x) * 4;  // flat (b*H + h) base, 4 wide
  const size_t mstr = (size_t)MC * H_DIM;
  size_t idx0 = (size_t)(seg * L_SEG) * BH + e4;
  float p0 = 1.f, p1 = 1.f, p2 = 1.f, p3 = 1.f;
  float c0 = 0.f, c1 = 0.f, c2 = 0.f, c3 = 0.f;
#pragma unroll 4
  for (int t = 0; t < L_SEG; t++) {
    size_t id = idx0 + (size_t)t * BH;
    ushort4 xp = *(const ushort4*)(projc + id);
    ushort4 ff = *(const ushort4*)(projc + mstr + id);
    float f0 = bf2f(ff.x), f1 = bf2f(ff.y), f2 = bf2f(ff.z), f3 = bf2f(ff.w);
    c0 = fmaf(f0, c0 - bf2f(xp.x), bf2f(xp.x));
    c1 = fmaf(f1, c1 - bf2f(xp.y), bf2f(xp.y));
    c2 = fmaf(f2, c2 - bf2f(xp.z), bf2f(xp.z));
    c3 = fmaf(f3, c3 - bf2f(xp.w), bf2f(xp.w));
    p0 *= f0; p1 *= f1; p2 *= f2; p3 *= f3;
  }
  int o = seg * BH + e4;
  *(float4*)(Pw + o) = make_float4(p0, p1, p2, p3);
  *(float4*)(Qw + o) = make_float4(c0, c1, c2, c3);
}

// ---------------------------------------------------------------------------
// Kernel 4b (prefix): chain segments exactly: c_out = P*c_in + Q.
// Also folds previous chunk's segmax into hm_state. 96 blocks x 256.
// ---------------------------------------------------------------------------
__global__ __launch_bounds__(256) void prefix_kernel(
    const float* __restrict__ Pw, const float* __restrict__ Qw,
    float* __restrict__ cin, float* __restrict__ c_state,
    const float* __restrict__ segmax, float* __restrict__ hm_state,
    int first, int hm_init) {
  int gid = blockIdx.x * 256 + threadIdx.x;
  float c = first ? 0.f : c_state[gid];
#pragma unroll
  for (int s = 0; s < S_SEG; s++) {
    cin[s * BH + gid] = c;
    c = fmaf(Pw[s * BH + gid], c, Qw[s * BH + gid]);
  }
  c_state[gid] = c;
  if (!first) {
    float m = segmax[gid];
#pragma unroll
    for (int s = 1; s < S_SEG; s++) m = fmaxf(m, segmax[s * BH + gid]);
    hm_state[gid] = hm_init ? m : fmaxf(hm_state[gid], m);
  }
}

// ---------------------------------------------------------------------------
// Kernel 4c (scan2): replay each segment from true c_in; h + segment max.
// ---------------------------------------------------------------------------
__global__ __launch_bounds__(128) void scan2_kernel(
    const unsigned short* __restrict__ projc,
    const float* __restrict__ cin, float* __restrict__ segmax) {
  int blk = blockIdx.x;
  int seg = blk / (BH / 512);
  int q   = blk % (BH / 512);
  int e4  = (q * 128 + threadIdx.x) * 4;
  const size_t mstr = (size_t)MC * H_DIM;
  size_t idx0 = (size_t)(seg * L_SEG) * BH + e4;
  int o = seg * BH + e4;
  float4 cv = *(const float4*)(cin + o);
  float c0 = cv.x, c1 = cv.y, c2 = cv.z, c3 = cv.w;
  float m0 = -1e30f, m1 = -1e30f, m2 = -1e30f, m3 = -1e30f;
#pragma unroll 2
  for (int t = 0; t < L_SEG; t++) {
    size_t id = idx0 + (size_t)t * BH;
    ushort4 xp = *(const ushort4*)(projc + id);
    ushort4 ff = *(const ushort4*)(projc + mstr + id);
    ushort4 rr = *(const ushort4*)(projc + 2 * mstr + id);
    ushort4 cx = *(const ushort4*)(projc + 3 * mstr + id);
    c0 = fmaf(bf2f(ff.x), c0 - bf2f(xp.x), bf2f(xp.x));
    c1 = fmaf(bf2f(ff.y), c1 - bf2f(xp.y), bf2f(xp.y));
    c2 = fmaf(bf2f(ff.z), c2 - bf2f(xp.z), bf2f(xp.z));
    c3 = fmaf(bf2f(ff.w), c3 - bf2f(xp.w), bf2f(xp.w));
    float h0 = fmaf(bf2f(rr.x), tanh_f(c0) - bf2f(cx.x), bf2f(cx.x));
    float h1 = fmaf(bf2f(rr.y), tanh_f(c1) - bf2f(cx.y), bf2f(cx.y));
    float h2 = fmaf(bf2f(rr.z), tanh_f(c2) - bf2f(cx.z), bf2f(cx.z));
    float h3 = fmaf(bf2f(rr.w), tanh_f(c3) - bf2f(cx.w), bf2f(cx.w));
    m0 = fmaxf(m0, h0); m1 = fmaxf(m1, h1);
    m2 = fmaxf(m2, h2); m3 = fmaxf(m3, h3);
  }
  *(float4*)(segmax + o) = make_float4(m0, m1, m2, m3);
}

// ---------------------------------------------------------------------------
// Kernel 4d: final pool = tanh(tanh(max(hm_state, last chunk's segmax)))
// ---------------------------------------------------------------------------
__global__ __launch_bounds__(256) void pool_final_kernel(
    const float* __restrict__ segmax, const float* __restrict__ hm_state,
    float* __restrict__ pooled) {
  int gid = blockIdx.x * 256 + threadIdx.x;
  float m = hm_state[gid];
#pragma unroll
  for (int s = 0; s < S_SEG; s++) m = fmaxf(m, segmax[s * BH + gid]);
  pooled[gid] = tanh_f(tanh_f(m));
}

// ---------------------------------------------------------------------------
// Kernel 5: classifier  logit[b][c] = pooled[b]·W_out[c] + b_out[c]
// ---------------------------------------------------------------------------
__global__ __launch_bounds__(64) void classifier_kernel(
    const float* __restrict__ pooled, const float* __restrict__ W_out,
    const float* __restrict__ b_out, float* __restrict__ out) {
  int b = blockIdx.x / C_DIM;
  int c = blockIdx.x % C_DIM;
  int lane = threadIdx.x;
  float s = 0.0f;
#pragma unroll
  for (int i = 0; i < H_DIM / 64; i++) {
    int h = i * 64 + lane;
    s += pooled[(size_t)b * H_DIM + h] * W_out[(size_t)c * H_DIM + h];
  }
#pragma unroll
  for (int off = 32; off; off >>= 1) s += __shfl_down(s, off, 64);
  if (lane == 0) out[b * C_DIM + c] = s + b_out[c];
}

// ---------------------------------------------------------------------------
extern "C" void kernel_launch(void* const* d_in, const int* in_sizes, int n_in,
                              void* d_out, int out_size, void* d_ws, size_t ws_size,
                              hipStream_t stream) {
  const int*   x     = (const int*)d_in[0];
  const float* table = (const float*)d_in[1];
  const float* W_x   = (const float*)d_in[2];
  const float* W_f   = (const float*)d_in[3];
  const float* b_f   = (const float*)d_in[4];
  const float* W_r   = (const float*)d_in[5];
  const float* b_r   = (const float*)d_in[6];
  const float* W_cx  = (const float*)d_in[7];
  const float* b_cx  = (const float*)d_in[8];
  const float* W_out = (const float*)d_in[9];
  const float* b_out = (const float*)d_in[10];

  // workspace layout (~245 MB; ws_size ~411 MB per harness fill size)
  char* ws = (char*)d_ws;
  size_t off = 0;
  unsigned short* wcat  = (unsigned short*)(ws + off); off += (size_t)N_DIM * K_DIM * 2;
  unsigned short* ebfc  = (unsigned short*)(ws + off); off += (size_t)MC * K_DIM * 2;
  unsigned short* projc = (unsigned short*)(ws + off); off += (size_t)4 * MC * H_DIM * 2;
  float* Pw     = (float*)(ws + off); off += (size_t)S_SEG * BH * 4;
  float* Qw     = (float*)(ws + off); off += (size_t)S_SEG * BH * 4;
  float* cin    = (float*)(ws + off); off += (size_t)S_SEG * BH * 4;
  float* segmax = (float*)(ws + off); off += (size_t)S_SEG * BH * 4;
  float* c_st   = (float*)(ws + off); off += (size_t)BH * 4;
  float* hm_st  = (float*)(ws + off); off += (size_t)BH * 4;
  float* pooled = (float*)(ws + off); off += (size_t)BH * 4;

  convert_w_kernel<<<(N_DIM * K_DIM / 4) / 256, 256, 0, stream>>>(W_x, W_f, W_r, W_cx, wcat);

  dim3 g(N_DIM / BN, MC / BM);   // (24, 256)
  for (int ch = 0; ch < NCHUNK; ch++) {
    gather_embed_kernel<<<(MC * K_DIM / 4) / 256, 256, 0, stream>>>(x + (size_t)ch * MC, table, ebfc);
    gemm_kernel<<<g, 256, 0, stream>>>(ebfc, wcat, b_f, b_r, b_cx, projc);
    scan1_kernel<<<S_SEG * (BH / 512), 128, 0, stream>>>(projc, Pw, Qw);
    prefix_kernel<<<BH / 256, 256, 0, stream>>>(Pw, Qw, cin, c_st, segmax, hm_st,
                                                ch == 0, ch == 1);
    scan2_kernel<<<S_SEG * (BH / 512), 128, 0, stream>>>(projc, cin, segmax);
  }
  pool_final_kernel<<<BH / 256, 256, 0, stream>>>(segmax, hm_st, pooled);
  classifier_kernel<<<B_DIM * C_DIM, 64, 0, stream>>>(pooled, W_out, b_out, (float*)d_out);
}